// Round 1
// baseline (37691.489 us; speedup 1.0000x reference)
//
#include <hip/hip_runtime.h>
#include <hip/hip_bf16.h>

#define NN 256
#define CCH 512
#define TT 4
#define SS 64
#define LL 256

typedef unsigned short u16;
typedef unsigned int u32;

__device__ __forceinline__ float bf2f(u32 h){
    return __uint_as_float(h << 16);
}
__device__ __forceinline__ u16 f2bf(float f){
    u32 u = __float_as_uint(f);
    u32 r = u + 0x7fffu + ((u >> 16) & 1u);
    return (u16)(r >> 16);
}

// ---------------------------------------------------------------------------
// Kernel 1: q,k,v = conv3(x, Wq/Wk/Wv).  One block = one (n,t) plane x 64 o's.
// x plane staged per-16-channel chunk into zero-padded 10x10 LDS tiles.
// Thread = (o = tid&63, wave g = tid>>6 owns rows 2g,2g+1 -> 16 spatial).
// Outputs written bf16 in [loc][n][c] layout (c contiguous, GEMM-friendly).
// ---------------------------------------------------------------------------
__global__ __launch_bounds__(256) void conv_qkv_kernel(
    const float* __restrict__ x,
    const float* __restrict__ Wq, const float* __restrict__ Wk, const float* __restrict__ Wv,
    u16* __restrict__ qb, u16* __restrict__ kb, u16* __restrict__ vb)
{
    __shared__ float xs[16][100];
    const int tid = threadIdx.x;
    const int n = blockIdx.x >> 2;
    const int t = blockIdx.x & 3;
    const int o = blockIdx.y * 64 + (tid & 63);
    const int g = tid >> 6;

    // zero whole LDS once: borders stay zero forever (padding)
    for (int i = tid; i < 1600; i += 256) (&xs[0][0])[i] = 0.f;

    float accq[16], acck[16], accv[16];
    #pragma unroll
    for (int i = 0; i < 16; ++i){ accq[i]=0.f; acck[i]=0.f; accv[i]=0.f; }

    const float* xplane = x + ((size_t)n*CCH*TT + t)*SS;
    const int cl = tid >> 4;           // channel within chunk 0..15
    const int p4 = (tid & 15) << 2;    // spatial 0..60 step 4
    const int r_st = p4 >> 3, col_st = p4 & 7;

    for (int c0 = 0; c0 < CCH; c0 += 16){
        __syncthreads();
        {   // stage 16 channels x 64 spatial (coalesced float4)
            float4 v = *(const float4*)(xplane + (size_t)(c0 + cl)*TT*SS + p4);
            float* dst = &xs[cl][(r_st+1)*10 + col_st + 1];
            dst[0]=v.x; dst[1]=v.y; dst[2]=v.z; dst[3]=v.w;
        }
        __syncthreads();
        for (int cc = 0; cc < 16; ++cc){
            const int c = c0 + cc;
            const float* wqp = Wq + ((size_t)o*CCH + c)*9;
            const float* wkp = Wk + ((size_t)o*CCH + c)*9;
            const float* wvp = Wv + ((size_t)o*CCH + c)*9;
            float xr[4][10];
            #pragma unroll
            for (int rr = 0; rr < 4; ++rr)
                #pragma unroll
                for (int c2 = 0; c2 < 10; ++c2)
                    xr[rr][c2] = xs[cc][(g*2+rr)*10 + c2];
            #pragma unroll
            for (int ky = 0; ky < 3; ++ky)
              #pragma unroll
              for (int kx = 0; kx < 3; ++kx){
                const float a = wqp[ky*3+kx];
                const float b = wkp[ky*3+kx];
                const float d = wvp[ky*3+kx];
                #pragma unroll
                for (int rr = 0; rr < 2; ++rr)
                  #pragma unroll
                  for (int col = 0; col < 8; ++col){
                    const float xv = xr[rr+ky][col+kx];
                    const int idx = rr*8 + col;
                    accq[idx] = fmaf(a, xv, accq[idx]);
                    acck[idx] = fmaf(b, xv, acck[idx]);
                    accv[idx] = fmaf(d, xv, accv[idx]);
                  }
              }
        }
    }
    #pragma unroll
    for (int idx = 0; idx < 16; ++idx){
        const int s = g*16 + idx;                      // s = h*8+w, h = 2g+idx/8
        const size_t off = ((size_t)(t*SS + s)*NN + n)*CCH + o;
        qb[off] = f2bf(accq[idx]);
        kb[off] = f2bf(acck[idx]);
        vb[off] = f2bf(accv[idx]);
    }
}

// ---------------------------------------------------------------------------
// Kernel 2: per-location attention.  Block = (loc, 16-row i-tile).
// Phase A: S = Q.K^T over c-chunks of 32 (fp32 in LDS), group-mask + softmax.
// Phase B: virt = P.V over c-chunks of 32 (V staged in same LDS buffer).
// ---------------------------------------------------------------------------
__global__ __launch_bounds__(256) void attn_kernel(
    const u16* __restrict__ qb, const u16* __restrict__ kb, const u16* __restrict__ vb,
    const int* __restrict__ roi, u16* __restrict__ virtb)
{
    __shared__ float Ks[256][36];   // K rows (then reused for V rows)
    __shared__ float Qs[16][36];
    __shared__ float Ps[16][260];   // softmax probs
    __shared__ int roi_s[256];

    const int loc = blockIdx.x;
    const int it  = blockIdx.y;
    const int tid = threadIdx.x;
    const int i   = tid >> 4;      // 0..15 row within tile
    const int cg  = tid & 15;      // column group
    const int ig  = it*16 + i;     // global row

    roi_s[tid] = roi[tid];

    float acc[16];
    #pragma unroll
    for (int jj = 0; jj < 16; ++jj) acc[jj] = 0.f;

    const u16* qbase = qb + (size_t)loc*NN*CCH;
    const u16* kbase = kb + (size_t)loc*NN*CCH;

    for (int c0 = 0; c0 < CCH; c0 += 32){
        __syncthreads();
        {   // stage K: thread = row j, 32 bf16 contiguous
            const uint4* src = (const uint4*)(kbase + (size_t)tid*CCH + c0);
            #pragma unroll
            for (int u = 0; u < 4; ++u){
                const uint4 v = src[u];
                float* dst = &Ks[tid][u*8];
                dst[0]=bf2f(v.x&0xffffu); dst[1]=bf2f(v.x>>16);
                dst[2]=bf2f(v.y&0xffffu); dst[3]=bf2f(v.y>>16);
                dst[4]=bf2f(v.z&0xffffu); dst[5]=bf2f(v.z>>16);
                dst[6]=bf2f(v.w&0xffffu); dst[7]=bf2f(v.w>>16);
            }
        }
        if (tid < 128){  // stage Q tile
            const int il = tid >> 3;
            const int c4 = (tid & 7) << 2;
            const u16* src = qbase + (size_t)(it*16 + il)*CCH + c0 + c4;
            const u32 w0 = *(const u32*)src;
            const u32 w1 = *(const u32*)(src + 2);
            Qs[il][c4+0]=bf2f(w0&0xffffu); Qs[il][c4+1]=bf2f(w0>>16);
            Qs[il][c4+2]=bf2f(w1&0xffffu); Qs[il][c4+3]=bf2f(w1>>16);
        }
        __syncthreads();
        #pragma unroll
        for (int c4 = 0; c4 < 8; ++c4){
            const float4 q4 = *(const float4*)&Qs[i][c4*4];
            #pragma unroll
            for (int jj = 0; jj < 16; ++jj){
                const float4 k4 = *(const float4*)&Ks[cg + 16*jj][c4*4];
                acc[jj] += q4.x*k4.x + q4.y*k4.y + q4.z*k4.z + q4.w*k4.w;
            }
        }
    }

    // mask + softmax (row i spread over 16 lanes, 16 j's each)
    const int my_roi = roi_s[ig];
    const float scale = 0.04419417382415922f;   // 1/sqrt(512)
    float sv[16];
    float m = -1e30f;
    #pragma unroll
    for (int jj = 0; jj < 16; ++jj){
        const int j = cg + 16*jj;
        sv[jj] = (roi_s[j] == my_roi) ? acc[jj]*scale : -1e30f;
        m = fmaxf(m, sv[jj]);
    }
    #pragma unroll
    for (int off = 1; off < 16; off <<= 1) m = fmaxf(m, __shfl_xor(m, off));
    float ssum = 0.f;
    float p[16];
    #pragma unroll
    for (int jj = 0; jj < 16; ++jj){
        const float e = (sv[jj] > -1e29f) ? __expf(sv[jj] - m) : 0.f;
        p[jj] = e;
        ssum += e;
    }
    #pragma unroll
    for (int off = 1; off < 16; off <<= 1) ssum += __shfl_xor(ssum, off);
    const float rinv = 1.f / ssum;   // diagonal always valid -> ssum > 0
    #pragma unroll
    for (int jj = 0; jj < 16; ++jj) Ps[i][cg + 16*jj] = p[jj]*rinv;

    // Phase B: virt[i][c] = sum_j P[i][j] * V[j][c]
    const u16* vbase = vb + (size_t)loc*NN*CCH;
    u16* obase = virtb + (size_t)loc*NN*CCH;
    for (int cb = 0; cb < 16; ++cb){
        __syncthreads();   // also publishes Ps on first iteration
        {
            const uint4* src = (const uint4*)(vbase + (size_t)tid*CCH + cb*32);
            #pragma unroll
            for (int u = 0; u < 4; ++u){
                const uint4 v = src[u];
                float* dst = &Ks[tid][u*8];
                dst[0]=bf2f(v.x&0xffffu); dst[1]=bf2f(v.x>>16);
                dst[2]=bf2f(v.y&0xffffu); dst[3]=bf2f(v.y>>16);
                dst[4]=bf2f(v.z&0xffffu); dst[5]=bf2f(v.z>>16);
                dst[6]=bf2f(v.w&0xffffu); dst[7]=bf2f(v.w>>16);
            }
        }
        __syncthreads();
        float a0 = 0.f, a1 = 0.f;
        #pragma unroll 8
        for (int j = 0; j < 256; j += 4){
            const float4 pv = *(const float4*)&Ps[i][j];
            const float2 v0 = *(const float2*)&Ks[j+0][cg*2];
            const float2 v1 = *(const float2*)&Ks[j+1][cg*2];
            const float2 v2 = *(const float2*)&Ks[j+2][cg*2];
            const float2 v3 = *(const float2*)&Ks[j+3][cg*2];
            a0 += pv.x*v0.x + pv.y*v1.x + pv.z*v2.x + pv.w*v3.x;
            a1 += pv.x*v0.y + pv.y*v1.y + pv.z*v2.y + pv.w*v3.y;
        }
        const int c = cb*32 + cg*2;
        *(u32*)(obase + (size_t)ig*CCH + c) = ((u32)f2bf(a1) << 16) | (u32)f2bf(a0);
    }
}

// ---------------------------------------------------------------------------
// Kernel 3: GroupNorm stats per sample (deterministic block reduction).
// ---------------------------------------------------------------------------
__global__ __launch_bounds__(256) void stats_kernel(
    const u16* __restrict__ virtb, float* __restrict__ musig)
{
    const int n = blockIdx.x;
    const int tid = threadIdx.x;
    float s = 0.f, q = 0.f;
    for (int loc = 0; loc < LL; ++loc){
        const u32 v = *(const u32*)(virtb + ((size_t)loc*NN + n)*CCH + 2*tid);
        const float a = bf2f(v & 0xffffu);
        const float b = bf2f(v >> 16);
        s += a + b;
        q += a*a + b*b;
    }
    #pragma unroll
    for (int off = 1; off < 64; off <<= 1){
        s += __shfl_xor(s, off);
        q += __shfl_xor(q, off);
    }
    __shared__ float red[8];
    const int wave = tid >> 6;
    if ((tid & 63) == 0){ red[wave*2] = s; red[wave*2+1] = q; }
    __syncthreads();
    if (tid == 0){
        const float S = red[0]+red[2]+red[4]+red[6];
        const float Q = red[1]+red[3]+red[5]+red[7];
        const float inv = 1.f/131072.f;   // C*T*H*W
        const float mval = S*inv;
        const float var = Q*inv - mval*mval;
        musig[2*n]   = mval;
        musig[2*n+1] = rsqrtf(var + 1e-5f);
    }
}

// ---------------------------------------------------------------------------
// Kernel 4: out = x + conv3(relu(gn(virt)), Wc).  Same structure as conv_qkv;
// GroupNorm+affine+ReLU fused into the LDS staging read; residual in epilogue.
// ---------------------------------------------------------------------------
__global__ __launch_bounds__(256) void conv_out_kernel(
    const u16* __restrict__ virtb, const float* __restrict__ Wc,
    const float* __restrict__ x, const float* __restrict__ gamma,
    const float* __restrict__ beta, const float* __restrict__ musig,
    float* __restrict__ out)
{
    __shared__ float xs[16][100];
    const int tid = threadIdx.x;
    const int n = blockIdx.x >> 2;
    const int t = blockIdx.x & 3;
    const int o = blockIdx.y * 64 + (tid & 63);
    const int g = tid >> 6;

    const float mu = musig[2*n];
    const float rsig = musig[2*n+1];

    for (int i = tid; i < 1600; i += 256) (&xs[0][0])[i] = 0.f;

    float acc[16];
    #pragma unroll
    for (int i = 0; i < 16; ++i) acc[i] = 0.f;

    const int s_ld = tid >> 2;          // spatial 0..63
    const int cq = (tid & 3) << 2;      // 4 channels each
    const int ldbase = ((s_ld>>3)+1)*10 + (s_ld&7) + 1;
    const u16* vrow = virtb + ((size_t)(t*SS + s_ld)*NN + n)*CCH;

    for (int c0 = 0; c0 < CCH; c0 += 16){
        __syncthreads();
        {
            const u32 w0 = *(const u32*)(vrow + c0 + cq);
            const u32 w1 = *(const u32*)(vrow + c0 + cq + 2);
            const float4 gv = *(const float4*)(gamma + c0 + cq);
            const float4 bv = *(const float4*)(beta  + c0 + cq);
            const float f0 = fmaxf((bf2f(w0 & 0xffffu) - mu)*rsig*gv.x + bv.x, 0.f);
            const float f1 = fmaxf((bf2f(w0 >> 16)     - mu)*rsig*gv.y + bv.y, 0.f);
            const float f2 = fmaxf((bf2f(w1 & 0xffffu) - mu)*rsig*gv.z + bv.z, 0.f);
            const float f3 = fmaxf((bf2f(w1 >> 16)     - mu)*rsig*gv.w + bv.w, 0.f);
            xs[cq+0][ldbase] = f0;
            xs[cq+1][ldbase] = f1;
            xs[cq+2][ldbase] = f2;
            xs[cq+3][ldbase] = f3;
        }
        __syncthreads();
        for (int cc = 0; cc < 16; ++cc){
            const int c = c0 + cc;
            const float* wp = Wc + ((size_t)o*CCH + c)*9;
            float xr[4][10];
            #pragma unroll
            for (int rr = 0; rr < 4; ++rr)
                #pragma unroll
                for (int c2 = 0; c2 < 10; ++c2)
                    xr[rr][c2] = xs[cc][(g*2+rr)*10 + c2];
            #pragma unroll
            for (int ky = 0; ky < 3; ++ky)
              #pragma unroll
              for (int kx = 0; kx < 3; ++kx){
                const float wv = wp[ky*3+kx];
                #pragma unroll
                for (int rr = 0; rr < 2; ++rr)
                  #pragma unroll
                  for (int col = 0; col < 8; ++col)
                    acc[rr*8+col] = fmaf(wv, xr[rr+ky][col+kx], acc[rr*8+col]);
              }
        }
    }
    const size_t base = (((size_t)n*CCH + o)*TT + t)*SS + g*16;
    #pragma unroll
    for (int q4 = 0; q4 < 4; ++q4){
        const float4 xv = *(const float4*)(x + base + q4*4);
        float4 r;
        r.x = xv.x + acc[q4*4+0];
        r.y = xv.y + acc[q4*4+1];
        r.z = xv.z + acc[q4*4+2];
        r.w = xv.w + acc[q4*4+3];
        *(float4*)(out + base + q4*4) = r;
    }
}

__global__ void sentinel_kernel(float* out){
    const size_t i = (size_t)blockIdx.x*256 + threadIdx.x;
    out[i] = 1.0e9f;   // distinctive marker: workspace too small
}

extern "C" void kernel_launch(void* const* d_in, const int* in_sizes, int n_in,
                              void* d_out, int out_size, void* d_ws, size_t ws_size,
                              hipStream_t stream)
{
    (void)in_sizes; (void)n_in; (void)out_size;
    const float* x   = (const float*)d_in[0];
    const int*   roi = (const int*)d_in[1];
    const float* Wq  = (const float*)d_in[2];
    const float* Wk  = (const float*)d_in[3];
    const float* Wv  = (const float*)d_in[4];
    const float* Wc  = (const float*)d_in[5];
    const float* gam = (const float*)d_in[6];
    const float* bet = (const float*)d_in[7];
    float* out = (float*)d_out;

    const size_t EL = 33554432ull;                 // N*C*T*H*W
    const size_t need = EL*2ull*4ull + 2048ull;    // q,k,v,virt bf16 + stats
    if (ws_size < need){
        sentinel_kernel<<<131072, 256, 0, stream>>>(out);
        return;
    }
    u16* qb    = (u16*)d_ws;
    u16* kb    = qb + EL;
    u16* vb    = kb + EL;
    u16* virtb = vb + EL;
    float* musig = (float*)(virtb + EL);

    conv_qkv_kernel<<<dim3(1024, 8), 256, 0, stream>>>(x, Wq, Wk, Wv, qb, kb, vb);
    attn_kernel<<<dim3(256, 16), 256, 0, stream>>>(qb, kb, vb, roi, virtb);
    stats_kernel<<<256, 256, 0, stream>>>(virtb, musig);
    conv_out_kernel<<<dim3(1024, 8), 256, 0, stream>>>(virtb, Wc, x, gam, bet, musig, out);
}

// Round 2
// 2692.678 us; speedup vs baseline: 13.9978x; 13.9978x over previous
//
#include <hip/hip_runtime.h>
#include <hip/hip_bf16.h>

#define NN 256
#define CCH 512
#define TT 4
#define SS 64
#define LL 256

typedef unsigned short u16;
typedef unsigned int u32;

typedef __bf16 bf16_t;
typedef bf16_t bf16x8 __attribute__((ext_vector_type(8)));
typedef float f32x16 __attribute__((ext_vector_type(16)));

__device__ __forceinline__ float bf2f(u32 h){
    return __uint_as_float(h << 16);
}
__device__ __forceinline__ u16 f2bf(float f){
    u32 u = __float_as_uint(f);
    u32 r = u + 0x7fffu + ((u >> 16) & 1u);
    return (u16)(r >> 16);
}
__device__ __forceinline__ bf16x8 ldg8(const u16* p){
    uint4 q = *(const uint4*)p;          // 16B aligned by construction
    return __builtin_bit_cast(bf16x8, q);
}
__device__ __forceinline__ bf16x8 ldl8(const u16* p){
    uint2 a = *(const uint2*)p;          // 8B aligned (stride 36 u16 = 72 B)
    uint2 b = *(const uint2*)(p + 4);
    uint4 q; q.x = a.x; q.y = a.y; q.z = b.x; q.w = b.y;
    return __builtin_bit_cast(bf16x8, q);
}

// ---------------------------------------------------------------------------
// Weight transpose: W[o][c][tap] fp32  ->  Wt[((tap*32 + c/16)*512 + o)*16 + c%16] bf16
// A-fragment for mfma_32x32x16 then loads 16B contiguous per lane, 1KB/wave coalesced.
// ---------------------------------------------------------------------------
__global__ __launch_bounds__(256) void wt_kernel(
    const float* __restrict__ W, u16* __restrict__ Wt)
{
    const int e = blockIdx.x * 256 + threadIdx.x;     // 0 .. 9*32*512*16-1
    const int cl  = e & 15;
    const int o   = (e >> 4) & 511;
    const int cg  = (e >> 13) & 31;
    const int tap = e >> 18;
    Wt[e] = f2bf(W[((size_t)o * CCH + cg * 16 + cl) * 9 + tap]);
}

// ---------------------------------------------------------------------------
// Implicit-GEMM conv via MFMA 32x32x16 bf16.
// Block: n = blockIdx.x (4 t-planes, 256 locs), o-group = blockIdx.y*128.
// Wave (w = tid>>6): wm = w&1 -> 2 m-tiles (64 o), wn = w>>1 -> 4 n-tiles (128 locs).
// K-loop: 16 chunks of 32 c; per chunk stage 4 planes to LDS (bf16, padded 10x10,
// c-stride 36), then 9 taps x 2 ksub x 8 MFMA.
// A lane: m = lane&31, k = (lane>>5)*8+j (16B global load from Wt).
// B lane: n = lane&31 -> (row,col) in 8x8, k likewise (2x ds_read_b64).
// D lane: row(o) = (reg&3)+8*(reg>>2)+4*(lane>>5), col(loc) = lane&31.
// ---------------------------------------------------------------------------
__global__ __launch_bounds__(256, 2) void conv_mfma_kernel(
    const float* __restrict__ x, const u16* __restrict__ Wt, u16* __restrict__ outb)
{
    __shared__ u16 lds[4 * 100 * 36];     // 28.8 KB
    const int tid = threadIdx.x;
    const int n  = blockIdx.x;
    const int ob = blockIdx.y * 128;
    const int lane = tid & 63;
    const int w  = tid >> 6;
    const int wm = w & 1, wn = w >> 1;
    const int h   = lane >> 5;
    const int col = lane & 31;
    const int r  = col >> 3, cc = col & 7;

    for (int i = tid; i < 7200; i += 256) ((u32*)lds)[i] = 0;   // borders = conv padding

    f32x16 acc[2][4];
    #pragma unroll
    for (int m = 0; m < 2; ++m)
      #pragma unroll
      for (int j = 0; j < 4; ++j)
        #pragma unroll
        for (int e = 0; e < 16; ++e) acc[m][j][e] = 0.f;

    // staging decode
    const int cp2 = tid >> 4;          // c-pair 0..15
    const int s4  = (tid & 15) << 2;   // spatial 0,4,..,60

    // B LDS per-lane bases (tap (0,0), ks 0) for the wave's 4 n-tiles
    int bbase[4];
    #pragma unroll
    for (int j = 0; j < 4; ++j){
        const int nt = wn * 4 + j;
        const int p = nt >> 1, sh = nt & 1;
        bbase[j] = (p * 100 + (sh * 4 + r) * 10 + cc) * 36 + h * 8;
    }
    const size_t abase = (size_t)(ob + wm * 64 + col) * 16 + h * 8;

    for (int ch = 0; ch < 16; ++ch){
        const int c0 = ch * 32;
        __syncthreads();
        #pragma unroll
        for (int p = 0; p < 4; ++p){
            const float* xr = x + (((size_t)n * CCH + c0 + 2 * cp2) * TT + p) * SS + s4;
            const float4 v0 = *(const float4*)xr;
            const float4 v1 = *(const float4*)(xr + 256);   // next c row (TT*SS floats)
            const float a0[4] = {v0.x, v0.y, v0.z, v0.w};
            const float a1[4] = {v1.x, v1.y, v1.z, v1.w};
            #pragma unroll
            for (int i = 0; i < 4; ++i){
                const int s = s4 + i;
                const int sp = ((s >> 3) + 1) * 10 + (s & 7) + 1;
                ((u32*)lds)[(p * 100 + sp) * 18 + cp2] =
                    (u32)f2bf(a0[i]) | ((u32)f2bf(a1[i]) << 16);
            }
        }
        __syncthreads();
        #pragma unroll
        for (int tap = 0; tap < 9; ++tap){
            const int tof = ((tap / 3) * 10 + (tap % 3)) * 36;
            #pragma unroll
            for (int ks = 0; ks < 2; ++ks){
                const size_t ai = (size_t)(tap * 32 + ch * 2 + ks) * 8192 + abase;
                const bf16x8 a0 = ldg8(Wt + ai);
                const bf16x8 a1 = ldg8(Wt + ai + 512);
                bf16x8 bfr[4];
                #pragma unroll
                for (int j = 0; j < 4; ++j)
                    bfr[j] = ldl8(&lds[bbase[j] + tof + ks * 16]);
                #pragma unroll
                for (int j = 0; j < 4; ++j){
                    acc[0][j] = __builtin_amdgcn_mfma_f32_32x32x16_bf16(a0, bfr[j], acc[0][j], 0, 0, 0);
                    acc[1][j] = __builtin_amdgcn_mfma_f32_32x32x16_bf16(a1, bfr[j], acc[1][j], 0, 0, 0);
                }
            }
        }
    }

    // epilogue: store bf16 to [loc][n][c]
    #pragma unroll
    for (int m = 0; m < 2; ++m){
        #pragma unroll
        for (int j = 0; j < 4; ++j){
            const int nt = wn * 4 + j;
            const int p = nt >> 1, sh = nt & 1;
            const int loc = p * SS + sh * 32 + col;
            u16* orow = outb + ((size_t)loc * NN + n) * CCH + ob + wm * 64 + m * 32;
            #pragma unroll
            for (int g2 = 0; g2 < 4; ++g2){
                uint2 val;
                val.x = (u32)f2bf(acc[m][j][g2 * 4 + 0]) | ((u32)f2bf(acc[m][j][g2 * 4 + 1]) << 16);
                val.y = (u32)f2bf(acc[m][j][g2 * 4 + 2]) | ((u32)f2bf(acc[m][j][g2 * 4 + 3]) << 16);
                *(uint2*)&orow[g2 * 8 + h * 4] = val;
            }
        }
    }
}

// ---------------------------------------------------------------------------
// conv_out: same MFMA structure; staging applies GroupNorm+affine+ReLU to virt;
// epilogue adds residual x and stores fp32 to [n][c][t][s].
// ---------------------------------------------------------------------------
__global__ __launch_bounds__(256, 2) void conv_out_mfma_kernel(
    const u16* __restrict__ virtb, const u16* __restrict__ Wt,
    const float* __restrict__ x, const float* __restrict__ gamma,
    const float* __restrict__ beta, const float* __restrict__ musig,
    float* __restrict__ out)
{
    __shared__ u16 lds[4 * 100 * 36];
    const int tid = threadIdx.x;
    const int n  = blockIdx.x;
    const int ob = blockIdx.y * 128;
    const int lane = tid & 63;
    const int w  = tid >> 6;
    const int wm = w & 1, wn = w >> 1;
    const int h   = lane >> 5;
    const int col = lane & 31;
    const int r  = col >> 3, cc = col & 7;

    const float mu   = musig[2 * n];
    const float rsig = musig[2 * n + 1];

    for (int i = tid; i < 7200; i += 256) ((u32*)lds)[i] = 0;

    f32x16 acc[2][4];
    #pragma unroll
    for (int m = 0; m < 2; ++m)
      #pragma unroll
      for (int j = 0; j < 4; ++j)
        #pragma unroll
        for (int e = 0; e < 16; ++e) acc[m][j][e] = 0.f;

    const int cp = tid & 15;        // c-pair (coalesced in [loc][n][c])
    const int sg = tid >> 4;        // 0..15

    int bbase[4];
    #pragma unroll
    for (int j = 0; j < 4; ++j){
        const int nt = wn * 4 + j;
        const int p = nt >> 1, sh = nt & 1;
        bbase[j] = (p * 100 + (sh * 4 + r) * 10 + cc) * 36 + h * 8;
    }
    const size_t abase = (size_t)(ob + wm * 64 + col) * 16 + h * 8;

    for (int ch = 0; ch < 16; ++ch){
        const int c0 = ch * 32;
        const float g0 = gamma[c0 + 2 * cp], g1 = gamma[c0 + 2 * cp + 1];
        const float b0 = beta [c0 + 2 * cp], b1 = beta [c0 + 2 * cp + 1];
        __syncthreads();
        #pragma unroll
        for (int p = 0; p < 4; ++p){
            #pragma unroll
            for (int i = 0; i < 4; ++i){
                const int s = sg * 4 + i;
                const u32 wv = *(const u32*)(virtb + ((size_t)(p * SS + s) * NN + n) * CCH + c0 + 2 * cp);
                const float f0 = fmaxf((bf2f(wv & 0xffffu) - mu) * rsig * g0 + b0, 0.f);
                const float f1 = fmaxf((bf2f(wv >> 16)     - mu) * rsig * g1 + b1, 0.f);
                const int sp = ((s >> 3) + 1) * 10 + (s & 7) + 1;
                ((u32*)lds)[(p * 100 + sp) * 18 + cp] =
                    (u32)f2bf(f0) | ((u32)f2bf(f1) << 16);
            }
        }
        __syncthreads();
        #pragma unroll
        for (int tap = 0; tap < 9; ++tap){
            const int tof = ((tap / 3) * 10 + (tap % 3)) * 36;
            #pragma unroll
            for (int ks = 0; ks < 2; ++ks){
                const size_t ai = (size_t)(tap * 32 + ch * 2 + ks) * 8192 + abase;
                const bf16x8 a0 = ldg8(Wt + ai);
                const bf16x8 a1 = ldg8(Wt + ai + 512);
                bf16x8 bfr[4];
                #pragma unroll
                for (int j = 0; j < 4; ++j)
                    bfr[j] = ldl8(&lds[bbase[j] + tof + ks * 16]);
                #pragma unroll
                for (int j = 0; j < 4; ++j){
                    acc[0][j] = __builtin_amdgcn_mfma_f32_32x32x16_bf16(a0, bfr[j], acc[0][j], 0, 0, 0);
                    acc[1][j] = __builtin_amdgcn_mfma_f32_32x32x16_bf16(a1, bfr[j], acc[1][j], 0, 0, 0);
                }
            }
        }
    }

    // epilogue: out = x + conv, fp32 [n][c][t][s]
    #pragma unroll
    for (int m = 0; m < 2; ++m){
        #pragma unroll
        for (int j = 0; j < 4; ++j){
            const int nt = wn * 4 + j;
            const int p = nt >> 1, sh = nt & 1;
            const int s = sh * 32 + col;
            #pragma unroll
            for (int g2 = 0; g2 < 4; ++g2){
                const int o0 = ob + wm * 64 + m * 32 + 8 * g2 + 4 * h;
                #pragma unroll
                for (int rr = 0; rr < 4; ++rr){
                    const size_t oi = (((size_t)n * CCH + o0 + rr) * TT + p) * SS + s;
                    out[oi] = x[oi] + acc[m][j][g2 * 4 + rr];
                }
            }
        }
    }
}

// ---------------------------------------------------------------------------
// Attention (unchanged from round 1): block = (loc, 16-row i-tile).
// ---------------------------------------------------------------------------
__global__ __launch_bounds__(256) void attn_kernel(
    const u16* __restrict__ qb, const u16* __restrict__ kb, const u16* __restrict__ vb,
    const int* __restrict__ roi, u16* __restrict__ virtb)
{
    __shared__ float Ks[256][36];
    __shared__ float Qs[16][36];
    __shared__ float Ps[16][260];
    __shared__ int roi_s[256];

    const int loc = blockIdx.x;
    const int it  = blockIdx.y;
    const int tid = threadIdx.x;
    const int i   = tid >> 4;
    const int cg  = tid & 15;
    const int ig  = it * 16 + i;

    roi_s[tid] = roi[tid];

    float acc[16];
    #pragma unroll
    for (int jj = 0; jj < 16; ++jj) acc[jj] = 0.f;

    const u16* qbase = qb + (size_t)loc * NN * CCH;
    const u16* kbase = kb + (size_t)loc * NN * CCH;

    for (int c0 = 0; c0 < CCH; c0 += 32){
        __syncthreads();
        {
            const uint4* src = (const uint4*)(kbase + (size_t)tid * CCH + c0);
            #pragma unroll
            for (int u = 0; u < 4; ++u){
                const uint4 v = src[u];
                float* dst = &Ks[tid][u * 8];
                dst[0]=bf2f(v.x&0xffffu); dst[1]=bf2f(v.x>>16);
                dst[2]=bf2f(v.y&0xffffu); dst[3]=bf2f(v.y>>16);
                dst[4]=bf2f(v.z&0xffffu); dst[5]=bf2f(v.z>>16);
                dst[6]=bf2f(v.w&0xffffu); dst[7]=bf2f(v.w>>16);
            }
        }
        if (tid < 128){
            const int il = tid >> 3;
            const int c4 = (tid & 7) << 2;
            const u16* src = qbase + (size_t)(it * 16 + il) * CCH + c0 + c4;
            const u32 w0 = *(const u32*)src;
            const u32 w1 = *(const u32*)(src + 2);
            Qs[il][c4+0]=bf2f(w0&0xffffu); Qs[il][c4+1]=bf2f(w0>>16);
            Qs[il][c4+2]=bf2f(w1&0xffffu); Qs[il][c4+3]=bf2f(w1>>16);
        }
        __syncthreads();
        #pragma unroll
        for (int c4 = 0; c4 < 8; ++c4){
            const float4 q4 = *(const float4*)&Qs[i][c4 * 4];
            #pragma unroll
            for (int jj = 0; jj < 16; ++jj){
                const float4 k4 = *(const float4*)&Ks[cg + 16 * jj][c4 * 4];
                acc[jj] += q4.x*k4.x + q4.y*k4.y + q4.z*k4.z + q4.w*k4.w;
            }
        }
    }

    const int my_roi = roi_s[ig];
    const float scale = 0.04419417382415922f;
    float sv[16];
    float m = -1e30f;
    #pragma unroll
    for (int jj = 0; jj < 16; ++jj){
        const int j = cg + 16 * jj;
        sv[jj] = (roi_s[j] == my_roi) ? acc[jj] * scale : -1e30f;
        m = fmaxf(m, sv[jj]);
    }
    #pragma unroll
    for (int off = 1; off < 16; off <<= 1) m = fmaxf(m, __shfl_xor(m, off));
    float ssum = 0.f;
    float p[16];
    #pragma unroll
    for (int jj = 0; jj < 16; ++jj){
        const float e = (sv[jj] > -1e29f) ? __expf(sv[jj] - m) : 0.f;
        p[jj] = e;
        ssum += e;
    }
    #pragma unroll
    for (int off = 1; off < 16; off <<= 1) ssum += __shfl_xor(ssum, off);
    const float rinv = 1.f / ssum;
    #pragma unroll
    for (int jj = 0; jj < 16; ++jj) Ps[i][cg + 16 * jj] = p[jj] * rinv;

    const u16* vbase = vb + (size_t)loc * NN * CCH;
    u16* obase = virtb + (size_t)loc * NN * CCH;
    for (int cb = 0; cb < 16; ++cb){
        __syncthreads();
        {
            const uint4* src = (const uint4*)(vbase + (size_t)tid * CCH + cb * 32);
            #pragma unroll
            for (int u = 0; u < 4; ++u){
                const uint4 v = src[u];
                float* dst = &Ks[tid][u * 8];
                dst[0]=bf2f(v.x&0xffffu); dst[1]=bf2f(v.x>>16);
                dst[2]=bf2f(v.y&0xffffu); dst[3]=bf2f(v.y>>16);
                dst[4]=bf2f(v.z&0xffffu); dst[5]=bf2f(v.z>>16);
                dst[6]=bf2f(v.w&0xffffu); dst[7]=bf2f(v.w>>16);
            }
        }
        __syncthreads();
        float a0 = 0.f, a1 = 0.f;
        #pragma unroll 8
        for (int j = 0; j < 256; j += 4){
            const float4 pv = *(const float4*)&Ps[i][j];
            const float2 v0 = *(const float2*)&Ks[j+0][cg*2];
            const float2 v1 = *(const float2*)&Ks[j+1][cg*2];
            const float2 v2 = *(const float2*)&Ks[j+2][cg*2];
            const float2 v3 = *(const float2*)&Ks[j+3][cg*2];
            a0 += pv.x*v0.x + pv.y*v1.x + pv.z*v2.x + pv.w*v3.x;
            a1 += pv.x*v0.y + pv.y*v1.y + pv.z*v2.y + pv.w*v3.y;
        }
        const int c = cb * 32 + cg * 2;
        *(u32*)(obase + (size_t)ig * CCH + c) = ((u32)f2bf(a1) << 16) | (u32)f2bf(a0);
    }
}

// ---------------------------------------------------------------------------
// GroupNorm stats per sample.
// ---------------------------------------------------------------------------
__global__ __launch_bounds__(256) void stats_kernel(
    const u16* __restrict__ virtb, float* __restrict__ musig)
{
    const int n = blockIdx.x;
    const int tid = threadIdx.x;
    float s = 0.f, q = 0.f;
    for (int loc = 0; loc < LL; ++loc){
        const u32 v = *(const u32*)(virtb + ((size_t)loc * NN + n) * CCH + 2 * tid);
        const float a = bf2f(v & 0xffffu);
        const float b = bf2f(v >> 16);
        s += a + b;
        q += a * a + b * b;
    }
    #pragma unroll
    for (int off = 1; off < 64; off <<= 1){
        s += __shfl_xor(s, off);
        q += __shfl_xor(q, off);
    }
    __shared__ float red[8];
    const int wave = tid >> 6;
    if ((tid & 63) == 0){ red[wave * 2] = s; red[wave * 2 + 1] = q; }
    __syncthreads();
    if (tid == 0){
        const float S = red[0] + red[2] + red[4] + red[6];
        const float Q = red[1] + red[3] + red[5] + red[7];
        const float inv = 1.f / 131072.f;
        const float mval = S * inv;
        const float var = Q * inv - mval * mval;
        musig[2 * n]     = mval;
        musig[2 * n + 1] = rsqrtf(var + 1e-5f);
    }
}

__global__ void sentinel_kernel(float* out){
    const size_t i = (size_t)blockIdx.x * 256 + threadIdx.x;
    out[i] = 1.0e9f;
}

extern "C" void kernel_launch(void* const* d_in, const int* in_sizes, int n_in,
                              void* d_out, int out_size, void* d_ws, size_t ws_size,
                              hipStream_t stream)
{
    (void)in_sizes; (void)n_in; (void)out_size;
    const float* x   = (const float*)d_in[0];
    const int*   roi = (const int*)d_in[1];
    const float* Wq  = (const float*)d_in[2];
    const float* Wk  = (const float*)d_in[3];
    const float* Wv  = (const float*)d_in[4];
    const float* Wc  = (const float*)d_in[5];
    const float* gam = (const float*)d_in[6];
    const float* bet = (const float*)d_in[7];
    float* out = (float*)d_out;

    const size_t EL = 33554432ull;                 // N*C*T*H*W
    const size_t need = EL * 2ull * 4ull + 2048ull;
    if (ws_size < need){
        sentinel_kernel<<<131072, 256, 0, stream>>>(out);
        return;
    }
    u16* qb    = (u16*)d_ws;
    u16* kb    = qb + EL;
    u16* vb    = kb + EL;
    u16* virtb = vb + EL;
    float* musig = (float*)(virtb + EL);

    // Transposed-weight scratch: d_out region is dead until conv_out (Wq/Wk/Wv),
    // qb region is dead after attn (Wc).  Stream order serializes everything.
    u16* WtA = (u16*)d_out;     // 2,359,296 u16 = 4.7 MB << 128 MB
    u16* WtC = qb;

    const dim3 cgrid(256, 4);

    wt_kernel<<<9216, 256, 0, stream>>>(Wq, WtA);
    conv_mfma_kernel<<<cgrid, 256, 0, stream>>>(x, WtA, qb);
    wt_kernel<<<9216, 256, 0, stream>>>(Wk, WtA);
    conv_mfma_kernel<<<cgrid, 256, 0, stream>>>(x, WtA, kb);
    wt_kernel<<<9216, 256, 0, stream>>>(Wv, WtA);
    conv_mfma_kernel<<<cgrid, 256, 0, stream>>>(x, WtA, vb);

    attn_kernel<<<dim3(256, 16), 256, 0, stream>>>(qb, kb, vb, roi, virtb);
    stats_kernel<<<256, 256, 0, stream>>>(virtb, musig);

    wt_kernel<<<9216, 256, 0, stream>>>(Wc, WtC);
    conv_out_mfma_kernel<<<cgrid, 256, 0, stream>>>(virtb, WtC, x, gam, bet, musig, out);
}